// Round 1
// baseline (138.308 us; speedup 1.0000x reference)
//
#include <hip/hip_runtime.h>
#include <math.h>

#define V_ 32000
#define E_ 1024
#define H_ 1024
#define S_ 2048

__device__ __forceinline__ float sigmoidf_(float x) { return 1.0f / (1.0f + expf(-x)); }

// ---------------- K1: LSTM gates + cell ----------------
// grid 1024 blocks, 256 threads. Block j computes gate rows j, j+1024, j+2048, j+3072.
__global__ __launch_bounds__(256) void k1_gates(
    const float* __restrict__ W_ih, const float* __restrict__ W_hh,
    const float* __restrict__ b_ih, const float* __restrict__ b_hh,
    const float* __restrict__ last_context, const float* __restrict__ emb,
    const int* __restrict__ word, const float* __restrict__ h0,
    const float* __restrict__ c0,
    float* __restrict__ out_ht, float* __restrict__ out_c,
    float* __restrict__ ws_ht)
{
    __shared__ float sbuf[4];
    int j = blockIdx.x;
    int tid = threadIdx.x;
    const float* embrow = emb + (size_t)word[0] * E_;
    float g[4];
    #pragma unroll
    for (int r = 0; r < 4; ++r) {
        int row = j + r * H_;
        const float* wi = W_ih + (size_t)row * (E_ + H_);
        const float* wh = W_hh + (size_t)row * H_;
        float acc = 0.f;
        #pragma unroll
        for (int it = 0; it < 2; ++it) {
            int idx = (tid + it * 256) * 4;
            float4 wv = *(const float4*)(wi + idx);
            float4 xv = (idx < H_) ? *(const float4*)(last_context + idx)
                                   : *(const float4*)(embrow + (idx - H_));
            acc = fmaf(wv.x, xv.x, acc); acc = fmaf(wv.y, xv.y, acc);
            acc = fmaf(wv.z, xv.z, acc); acc = fmaf(wv.w, xv.w, acc);
        }
        {
            int idx = tid * 4;
            float4 wv = *(const float4*)(wh + idx);
            float4 hv = *(const float4*)(h0 + idx);
            acc = fmaf(wv.x, hv.x, acc); acc = fmaf(wv.y, hv.y, acc);
            acc = fmaf(wv.z, hv.z, acc); acc = fmaf(wv.w, hv.w, acc);
        }
        #pragma unroll
        for (int m = 32; m; m >>= 1) acc += __shfl_down(acc, m, 64);
        __syncthreads();
        if ((tid & 63) == 0) sbuf[tid >> 6] = acc;
        __syncthreads();
        g[r] = sbuf[0] + sbuf[1] + sbuf[2] + sbuf[3];
    }
    if (tid == 0) {
        float gi = g[0] + b_ih[j]          + b_hh[j];
        float gf = g[1] + b_ih[j + H_]     + b_hh[j + H_];
        float gg = g[2] + b_ih[j + 2*H_]   + b_hh[j + 2*H_];
        float go = g[3] + b_ih[j + 3*H_]   + b_hh[j + 3*H_];
        float c  = sigmoidf_(gf) * c0[j] + sigmoidf_(gi) * tanhf(gg);
        float ht = sigmoidf_(go) * tanhf(c);
        out_c[j]  = c;
        out_ht[j] = ht;
        ws_ht[j]  = ht;
    }
}

// ---------------- K2: q = Wa_h @ ht + b_attn ----------------
// grid 1024 blocks, 64 threads (one wave per row)
__global__ __launch_bounds__(64) void k2_q(
    const float* __restrict__ W_attn, const float* __restrict__ b_attn,
    const float* __restrict__ ht, float* __restrict__ q)
{
    int h = blockIdx.x;
    int lane = threadIdx.x;
    const float* row = W_attn + (size_t)h * (E_ + H_);  // first H_ cols = Wa_h
    float acc = 0.f;
    #pragma unroll
    for (int it = 0; it < 4; ++it) {
        int idx = (lane + it * 64) * 4;
        float4 wv = *(const float4*)(row + idx);
        float4 hv = *(const float4*)(ht + idx);
        acc = fmaf(wv.x, hv.x, acc); acc = fmaf(wv.y, hv.y, acc);
        acc = fmaf(wv.z, hv.z, acc); acc = fmaf(wv.w, hv.w, acc);
    }
    #pragma unroll
    for (int m = 32; m; m >>= 1) acc += __shfl_down(acc, m, 64);
    if (lane == 0) q[h] = acc + b_attn[h];
}

// ---------------- K3: scores = tanh(enc @ Wa_e^T + q) @ v (fused) ----------------
// grid (S/64, H/64) = (32,16), block 256 (16x16 threads, 4x4 microtile)
__global__ __launch_bounds__(256) void k3_scores(
    const float* __restrict__ enc, const float* __restrict__ W_attn,
    const float* __restrict__ q, const float* __restrict__ v,
    float* __restrict__ scores)
{
    __shared__ float As[16][68];   // [k][row], padded
    __shared__ float Bs[16][68];
    int s0 = blockIdx.x * 64, h0 = blockIdx.y * 64;
    int tid = threadIdx.x;
    int tx = tid & 15, ty = tid >> 4;
    float acc[4][4] = {};
    int lr = tid >> 2, lk4 = (tid & 3) * 4;
    const float* arow = enc    + (size_t)(s0 + lr) * E_ + lk4;
    const float* brow = W_attn + (size_t)(h0 + lr) * (E_ + H_) + H_ + lk4;  // Wa_e
    for (int k0 = 0; k0 < E_; k0 += 16) {
        float4 av = *(const float4*)(arow + k0);
        float4 bv = *(const float4*)(brow + k0);
        __syncthreads();
        As[lk4+0][lr] = av.x; As[lk4+1][lr] = av.y; As[lk4+2][lr] = av.z; As[lk4+3][lr] = av.w;
        Bs[lk4+0][lr] = bv.x; Bs[lk4+1][lr] = bv.y; Bs[lk4+2][lr] = bv.z; Bs[lk4+3][lr] = bv.w;
        __syncthreads();
        #pragma unroll
        for (int k = 0; k < 16; ++k) {
            float4 a4 = *(const float4*)(&As[k][ty * 4]);
            float4 b4 = *(const float4*)(&Bs[k][tx * 4]);
            float a[4] = {a4.x, a4.y, a4.z, a4.w};
            float b[4] = {b4.x, b4.y, b4.z, b4.w};
            #pragma unroll
            for (int r = 0; r < 4; ++r)
                #pragma unroll
                for (int c = 0; c < 4; ++c)
                    acc[r][c] = fmaf(a[r], b[c], acc[r][c]);
        }
    }
    float qv[4], vv[4];
    #pragma unroll
    for (int c = 0; c < 4; ++c) {
        qv[c] = q[h0 + tx * 4 + c];
        vv[c] = v[h0 + tx * 4 + c];
    }
    #pragma unroll
    for (int r = 0; r < 4; ++r) {
        float p = 0.f;
        #pragma unroll
        for (int c = 0; c < 4; ++c)
            p += tanhf(acc[r][c] + qv[c]) * vv[c];
        #pragma unroll
        for (int m = 8; m; m >>= 1) p += __shfl_xor(p, m, 64);
        if (tx == 0) atomicAdd(&scores[s0 + ty * 4 + r], p);
    }
}

// ---------------- K4: w = softmax(scores) ----------------
// single block, 256 threads, 8 elems each
__global__ __launch_bounds__(256) void k4_softmax(
    const float* __restrict__ scores, float* __restrict__ w_out, float* __restrict__ w_ws)
{
    __shared__ float sm[4];
    int tid = threadIdx.x;
    float x[8];
    float m = -1e30f;
    #pragma unroll
    for (int i = 0; i < 8; ++i) { x[i] = scores[tid + i * 256]; m = fmaxf(m, x[i]); }
    #pragma unroll
    for (int s = 32; s; s >>= 1) m = fmaxf(m, __shfl_xor(m, s, 64));
    if ((tid & 63) == 0) sm[tid >> 6] = m;
    __syncthreads();
    m = fmaxf(fmaxf(sm[0], sm[1]), fmaxf(sm[2], sm[3]));
    float sum = 0.f;
    #pragma unroll
    for (int i = 0; i < 8; ++i) { x[i] = expf(x[i] - m); sum += x[i]; }
    #pragma unroll
    for (int s = 32; s; s >>= 1) sum += __shfl_xor(sum, s, 64);
    __syncthreads();
    if ((tid & 63) == 0) sm[tid >> 6] = sum;
    __syncthreads();
    sum = sm[0] + sm[1] + sm[2] + sm[3];
    float inv = 1.0f / sum;
    #pragma unroll
    for (int i = 0; i < 8; ++i) {
        float wv = x[i] * inv;
        w_out[tid + i * 256] = wv;
        w_ws[tid + i * 256]  = wv;
    }
}

// ---------------- K5: context = w @ enc ----------------
// grid (4, 32), block 256; thread -> one e column, 64 s-rows per block
__global__ __launch_bounds__(256) void k5_context(
    const float* __restrict__ enc, const float* __restrict__ w,
    float* __restrict__ context)
{
    int e = blockIdx.x * 256 + threadIdx.x;
    int s_begin = blockIdx.y * 64;
    float acc = 0.f;
    #pragma unroll 4
    for (int s = s_begin; s < s_begin + 64; ++s)
        acc = fmaf(w[s], enc[(size_t)s * E_ + e], acc);
    atomicAdd(&context[e], acc);
}

// ---------------- K6: ht_tilda = tanh(W_ah @ [context, ht] + b_ah) ----------------
__global__ __launch_bounds__(64) void k6_htilda(
    const float* __restrict__ W_ah, const float* __restrict__ b_ah,
    const float* __restrict__ context, const float* __restrict__ ht,
    float* __restrict__ out_htt, float* __restrict__ ws_htt)
{
    int h = blockIdx.x;
    int lane = threadIdx.x;
    const float* row = W_ah + (size_t)h * (E_ + H_);
    float acc = 0.f;
    #pragma unroll
    for (int it = 0; it < 8; ++it) {
        int idx = (lane + it * 64) * 4;
        float4 wv = *(const float4*)(row + idx);
        float4 xv = (idx < E_) ? *(const float4*)(context + idx)
                               : *(const float4*)(ht + idx - E_);
        acc = fmaf(wv.x, xv.x, acc); acc = fmaf(wv.y, xv.y, acc);
        acc = fmaf(wv.z, xv.z, acc); acc = fmaf(wv.w, xv.w, acc);
    }
    #pragma unroll
    for (int m = 32; m; m >>= 1) acc += __shfl_down(acc, m, 64);
    if (lane == 0) {
        float val = tanhf(acc + b_ah[h]);
        out_htt[h] = val;
        ws_htt[h]  = val;
    }
}

// ---------------- K7: logits = W_out @ ht_tilda + b_out ----------------
// grid 8000, block 256 (4 waves, one row per wave)
__global__ __launch_bounds__(256) void k7_logits(
    const float* __restrict__ W_out, const float* __restrict__ b_out,
    const float* __restrict__ ht_tilda, float* __restrict__ logits)
{
    int row = blockIdx.x * 4 + (threadIdx.x >> 6);
    int lane = threadIdx.x & 63;
    const float* wr = W_out + (size_t)row * H_;
    float acc = 0.f;
    #pragma unroll
    for (int it = 0; it < 4; ++it) {
        int idx = (lane + it * 64) * 4;
        float4 wv = *(const float4*)(wr + idx);
        float4 hv = *(const float4*)(ht_tilda + idx);
        acc = fmaf(wv.x, hv.x, acc); acc = fmaf(wv.y, hv.y, acc);
        acc = fmaf(wv.z, hv.z, acc); acc = fmaf(wv.w, hv.w, acc);
    }
    #pragma unroll
    for (int m = 32; m; m >>= 1) acc += __shfl_down(acc, m, 64);
    if (lane == 0) logits[row] = acc + b_out[row];
}

// ---------------- K8: lse = logsumexp(logits) ----------------
__global__ __launch_bounds__(1024) void k8_lse(
    const float* __restrict__ logits, float* __restrict__ lse)
{
    __shared__ float sm[16];
    int tid = threadIdx.x;
    float m = -1e30f;
    for (int i = tid; i < V_; i += 1024) m = fmaxf(m, logits[i]);
    #pragma unroll
    for (int s = 32; s; s >>= 1) m = fmaxf(m, __shfl_xor(m, s, 64));
    if ((tid & 63) == 0) sm[tid >> 6] = m;
    __syncthreads();
    float m_all = sm[0];
    #pragma unroll
    for (int i = 1; i < 16; ++i) m_all = fmaxf(m_all, sm[i]);
    float sum = 0.f;
    for (int i = tid; i < V_; i += 1024) sum += expf(logits[i] - m_all);
    #pragma unroll
    for (int s = 32; s; s >>= 1) sum += __shfl_xor(sum, s, 64);
    __syncthreads();
    if ((tid & 63) == 0) sm[tid >> 6] = sum;
    __syncthreads();
    if (tid == 0) {
        float s_all = 0.f;
        #pragma unroll
        for (int i = 0; i < 16; ++i) s_all += sm[i];
        lse[0] = m_all + logf(s_all);
    }
}

// ---------------- K9: out = logits - lse ----------------
__global__ __launch_bounds__(256) void k9_logsoftmax(
    float* __restrict__ out, const float* __restrict__ lse)
{
    int i = blockIdx.x * 256 + threadIdx.x;
    if (i < V_) out[i] -= lse[0];
}

extern "C" void kernel_launch(void* const* d_in, const int* in_sizes, int n_in,
                              void* d_out, int out_size, void* d_ws, size_t ws_size,
                              hipStream_t stream) {
    const float* enc          = (const float*)d_in[0];
    const int*   word         = (const int*)  d_in[1];
    const float* last_context = (const float*)d_in[2];
    const float* h0           = (const float*)d_in[3];
    const float* c0           = (const float*)d_in[4];
    const float* emb          = (const float*)d_in[5];
    const float* W_ih         = (const float*)d_in[6];
    const float* W_hh         = (const float*)d_in[7];
    const float* b_ih         = (const float*)d_in[8];
    const float* b_hh         = (const float*)d_in[9];
    const float* W_attn       = (const float*)d_in[10];
    const float* b_attn       = (const float*)d_in[11];
    const float* v            = (const float*)d_in[12];
    const float* W_ah         = (const float*)d_in[13];
    const float* b_ah         = (const float*)d_in[14];
    const float* W_out        = (const float*)d_in[15];
    const float* b_out        = (const float*)d_in[16];

    float* out        = (float*)d_out;
    float* out_logits = out;                 // 32000
    float* out_ht     = out + V_;            // 1024
    float* out_c      = out + V_ + H_;       // 1024
    float* out_htt    = out + V_ + 2 * H_;   // 1024
    float* out_w      = out + V_ + 3 * H_;   // 2048

    float* ws        = (float*)d_ws;
    float* ws_ht     = ws;          // 1024
    float* ws_q      = ws + 1024;   // 1024
    float* ws_scores = ws + 2048;   // 2048
    float* ws_w      = ws + 4096;   // 2048
    float* ws_ctx    = ws + 6144;   // 1024
    float* ws_htt    = ws + 7168;   // 1024
    float* ws_lse    = ws + 8192;   // 1

    hipMemsetAsync(ws_scores, 0, S_ * sizeof(float), stream);
    hipMemsetAsync(ws_ctx,    0, E_ * sizeof(float), stream);

    k1_gates<<<1024, 256, 0, stream>>>(W_ih, W_hh, b_ih, b_hh, last_context, emb,
                                       word, h0, c0, out_ht, out_c, ws_ht);
    k2_q<<<1024, 64, 0, stream>>>(W_attn, b_attn, ws_ht, ws_q);
    k3_scores<<<dim3(S_ / 64, H_ / 64), 256, 0, stream>>>(enc, W_attn, ws_q, v, ws_scores);
    k4_softmax<<<1, 256, 0, stream>>>(ws_scores, out_w, ws_w);
    k5_context<<<dim3(4, 32), 256, 0, stream>>>(enc, ws_w, ws_ctx);
    k6_htilda<<<1024, 64, 0, stream>>>(W_ah, b_ah, ws_ctx, ws_ht, out_htt, ws_htt);
    k7_logits<<<8000, 256, 0, stream>>>(W_out, b_out, ws_htt, out_logits);
    k8_lse<<<1, 1024, 0, stream>>>(out_logits, ws_lse);
    k9_logsoftmax<<<(V_ + 255) / 256, 256, 0, stream>>>(out_logits, ws_lse);
}

// Round 2
// 110.623 us; speedup vs baseline: 1.2503x; 1.2503x over previous
//
#include <hip/hip_runtime.h>
#include <math.h>

#define V_ 32000
#define E_ 1024
#define H_ 1024
#define S_ 2048

typedef __attribute__((ext_vector_type(8))) short bf16x8;
typedef __attribute__((ext_vector_type(8))) unsigned short u16x8;
typedef __attribute__((ext_vector_type(4))) float f32x4;

__device__ __forceinline__ float sigmoidf_(float x) { return 1.0f / (1.0f + expf(-x)); }

__device__ __forceinline__ unsigned short f2bf(float f) {
    unsigned int u = __builtin_bit_cast(unsigned int, f);
    unsigned int r = (u + 0x7fffu + ((u >> 16) & 1u)) >> 16;
    return (unsigned short)r;
}

__device__ __forceinline__ u16x8 pack8(float4 a, float4 b) {
    u16x8 p;
    p[0] = f2bf(a.x); p[1] = f2bf(a.y); p[2] = f2bf(a.z); p[3] = f2bf(a.w);
    p[4] = f2bf(b.x); p[5] = f2bf(b.y); p[6] = f2bf(b.z); p[7] = f2bf(b.w);
    return p;
}

// ---------------- K1: LSTM gates + cell ----------------
__global__ __launch_bounds__(256) void k1_gates(
    const float* __restrict__ W_ih, const float* __restrict__ W_hh,
    const float* __restrict__ b_ih, const float* __restrict__ b_hh,
    const float* __restrict__ last_context, const float* __restrict__ emb,
    const int* __restrict__ word, const float* __restrict__ h0,
    const float* __restrict__ c0,
    float* __restrict__ out_ht, float* __restrict__ out_c,
    float* __restrict__ ws_ht)
{
    __shared__ float sbuf[4];
    int j = blockIdx.x;
    int tid = threadIdx.x;
    const float* embrow = emb + (size_t)word[0] * E_;
    float g[4];
    #pragma unroll
    for (int r = 0; r < 4; ++r) {
        int row = j + r * H_;
        const float* wi = W_ih + (size_t)row * (E_ + H_);
        const float* wh = W_hh + (size_t)row * H_;
        float acc = 0.f;
        #pragma unroll
        for (int it = 0; it < 2; ++it) {
            int idx = (tid + it * 256) * 4;
            float4 wv = *(const float4*)(wi + idx);
            float4 xv = (idx < H_) ? *(const float4*)(last_context + idx)
                                   : *(const float4*)(embrow + (idx - H_));
            acc = fmaf(wv.x, xv.x, acc); acc = fmaf(wv.y, xv.y, acc);
            acc = fmaf(wv.z, xv.z, acc); acc = fmaf(wv.w, xv.w, acc);
        }
        {
            int idx = tid * 4;
            float4 wv = *(const float4*)(wh + idx);
            float4 hv = *(const float4*)(h0 + idx);
            acc = fmaf(wv.x, hv.x, acc); acc = fmaf(wv.y, hv.y, acc);
            acc = fmaf(wv.z, hv.z, acc); acc = fmaf(wv.w, hv.w, acc);
        }
        #pragma unroll
        for (int m = 32; m; m >>= 1) acc += __shfl_down(acc, m, 64);
        __syncthreads();
        if ((tid & 63) == 0) sbuf[tid >> 6] = acc;
        __syncthreads();
        g[r] = sbuf[0] + sbuf[1] + sbuf[2] + sbuf[3];
    }
    if (tid == 0) {
        float gi = g[0] + b_ih[j]          + b_hh[j];
        float gf = g[1] + b_ih[j + H_]     + b_hh[j + H_];
        float gg = g[2] + b_ih[j + 2*H_]   + b_hh[j + 2*H_];
        float go = g[3] + b_ih[j + 3*H_]   + b_hh[j + 3*H_];
        float c  = sigmoidf_(gf) * c0[j] + sigmoidf_(gi) * tanhf(gg);
        float ht = sigmoidf_(go) * tanhf(c);
        out_c[j]  = c;
        out_ht[j] = ht;
        ws_ht[j]  = ht;
    }
}

// ---------------- K2: q = Wa_h @ ht + b_attn ----------------
__global__ __launch_bounds__(64) void k2_q(
    const float* __restrict__ W_attn, const float* __restrict__ b_attn,
    const float* __restrict__ ht, float* __restrict__ q)
{
    int h = blockIdx.x;
    int lane = threadIdx.x;
    const float* row = W_attn + (size_t)h * (E_ + H_);
    float acc = 0.f;
    #pragma unroll
    for (int it = 0; it < 4; ++it) {
        int idx = (lane + it * 64) * 4;
        float4 wv = *(const float4*)(row + idx);
        float4 hv = *(const float4*)(ht + idx);
        acc = fmaf(wv.x, hv.x, acc); acc = fmaf(wv.y, hv.y, acc);
        acc = fmaf(wv.z, hv.z, acc); acc = fmaf(wv.w, hv.w, acc);
    }
    #pragma unroll
    for (int m = 32; m; m >>= 1) acc += __shfl_down(acc, m, 64);
    if (lane == 0) q[h] = acc + b_attn[h];
}

// ---------------- K3: scores = tanh(enc @ Wa_e^T + q) @ v — bf16 MFMA ----------------
// Tile BM=128 x BN=128, BK=32. Grid (16,8), 256 threads = 4 waves (2x2, each 64x64).
// LDS physical layout: chunk ch = row*4 + p (16B chunks); logical k-chunk
// c = p ^ ((row>>1)&3) (XOR swizzle -> 2-way reads, linear writes).
__global__ __launch_bounds__(256) void k3_mfma(
    const float* __restrict__ enc, const float* __restrict__ W_attn,
    const float* __restrict__ q, const float* __restrict__ v,
    float* __restrict__ scores)
{
    __shared__ unsigned short As[128 * 32];
    __shared__ unsigned short Bs[128 * 32];
    int s0 = blockIdx.x * 128, h0 = blockIdx.y * 128;
    int tid = threadIdx.x;
    int wave = tid >> 6, lane = tid & 63;
    int wr = (wave >> 1) * 64;  // wave row origin within tile
    int wc = (wave & 1) * 64;   // wave col origin within tile

    // staging: thread owns physical chunks ch = tid and tid+256
    int pr0 = tid >> 2;              // physical row (chunk i=0)
    int pr1 = pr0 + 64;              // chunk i=1
    int pp  = tid & 3;               // physical chunk-in-row
    int lc  = pp ^ ((pr0 >> 1) & 3); // logical k-chunk (identical for pr1)

    const float* aS0 = enc    + (size_t)(s0 + pr0) * E_ + lc * 8;
    const float* aS1 = enc    + (size_t)(s0 + pr1) * E_ + lc * 8;
    const float* bS0 = W_attn + (size_t)(h0 + pr0) * (E_ + H_) + H_ + lc * 8;
    const float* bS1 = W_attn + (size_t)(h0 + pr1) * (E_ + H_) + H_ + lc * 8;
    u16x8* aD0 = (u16x8*)&As[(size_t)tid * 8];
    u16x8* aD1 = (u16x8*)&As[(size_t)(tid + 256) * 8];
    u16x8* bD0 = (u16x8*)&Bs[(size_t)tid * 8];
    u16x8* bD1 = (u16x8*)&Bs[(size_t)(tid + 256) * 8];

    f32x4 acc[4][4];
    #pragma unroll
    for (int m = 0; m < 4; ++m)
        #pragma unroll
        for (int n = 0; n < 4; ++n)
            acc[m][n] = (f32x4){0.f, 0.f, 0.f, 0.f};

    // fragment read offsets (in shorts): row*32 + p*8, p = g ^ ((row>>1)&3)
    int fc = lane & 15;   // fragment row-within-16 / col-within-16
    int g  = lane >> 4;   // k-chunk group
    int aOff[4], bOff[4];
    #pragma unroll
    for (int m = 0; m < 4; ++m) {
        int row = wr + m * 16 + fc;
        aOff[m] = row * 32 + (g ^ ((row >> 1) & 3)) * 8;
    }
    #pragma unroll
    for (int n = 0; n < 4; ++n) {
        int row = wc + n * 16 + fc;
        bOff[n] = row * 32 + (g ^ ((row >> 1) & 3)) * 8;
    }

    for (int k0 = 0; k0 < E_; k0 += 32) {
        float4 a00 = *(const float4*)(aS0 + k0);
        float4 a01 = *(const float4*)(aS0 + k0 + 4);
        float4 a10 = *(const float4*)(aS1 + k0);
        float4 a11 = *(const float4*)(aS1 + k0 + 4);
        float4 b00 = *(const float4*)(bS0 + k0);
        float4 b01 = *(const float4*)(bS0 + k0 + 4);
        float4 b10 = *(const float4*)(bS1 + k0);
        float4 b11 = *(const float4*)(bS1 + k0 + 4);
        __syncthreads();   // previous iteration's reads complete
        *aD0 = pack8(a00, a01);
        *aD1 = pack8(a10, a11);
        *bD0 = pack8(b00, b01);
        *bD1 = pack8(b10, b11);
        __syncthreads();
        bf16x8 af[4], bf[4];
        #pragma unroll
        for (int m = 0; m < 4; ++m) af[m] = *(const bf16x8*)&As[aOff[m]];
        #pragma unroll
        for (int n = 0; n < 4; ++n) bf[n] = *(const bf16x8*)&Bs[bOff[n]];
        #pragma unroll
        for (int m = 0; m < 4; ++m)
            #pragma unroll
            for (int n = 0; n < 4; ++n)
                acc[m][n] = __builtin_amdgcn_mfma_f32_16x16x32_bf16(
                    af[m], bf[n], acc[m][n], 0, 0, 0);
    }

    // epilogue: p[row] += sum_col tanh(acc + q[col]) * v[col]
    float qv[4], vv[4];
    #pragma unroll
    for (int n = 0; n < 4; ++n) {
        int hc = h0 + wc + n * 16 + fc;
        qv[n] = q[hc];
        vv[n] = v[hc];
    }
    #pragma unroll
    for (int m = 0; m < 4; ++m) {
        #pragma unroll
        for (int j = 0; j < 4; ++j) {
            float p = 0.f;
            #pragma unroll
            for (int n = 0; n < 4; ++n)
                p += tanhf(acc[m][n][j] + qv[n]) * vv[n];
            #pragma unroll
            for (int mask = 8; mask; mask >>= 1) p += __shfl_xor(p, mask, 64);
            if (fc == 0)
                atomicAdd(&scores[s0 + wr + m * 16 + g * 4 + j], p);
        }
    }
}

// ---------------- K4: w = softmax(scores) ----------------
__global__ __launch_bounds__(256) void k4_softmax(
    const float* __restrict__ scores, float* __restrict__ w_out, float* __restrict__ w_ws)
{
    __shared__ float sm[4];
    int tid = threadIdx.x;
    float x[8];
    float m = -1e30f;
    #pragma unroll
    for (int i = 0; i < 8; ++i) { x[i] = scores[tid + i * 256]; m = fmaxf(m, x[i]); }
    #pragma unroll
    for (int s = 32; s; s >>= 1) m = fmaxf(m, __shfl_xor(m, s, 64));
    if ((tid & 63) == 0) sm[tid >> 6] = m;
    __syncthreads();
    m = fmaxf(fmaxf(sm[0], sm[1]), fmaxf(sm[2], sm[3]));
    float sum = 0.f;
    #pragma unroll
    for (int i = 0; i < 8; ++i) { x[i] = expf(x[i] - m); sum += x[i]; }
    #pragma unroll
    for (int s = 32; s; s >>= 1) sum += __shfl_xor(sum, s, 64);
    __syncthreads();
    if ((tid & 63) == 0) sm[tid >> 6] = sum;
    __syncthreads();
    sum = sm[0] + sm[1] + sm[2] + sm[3];
    float inv = 1.0f / sum;
    #pragma unroll
    for (int i = 0; i < 8; ++i) {
        float wv = x[i] * inv;
        w_out[tid + i * 256] = wv;
        w_ws[tid + i * 256]  = wv;
    }
}

// ---------------- K5: context = w @ enc ----------------
__global__ __launch_bounds__(256) void k5_context(
    const float* __restrict__ enc, const float* __restrict__ w,
    float* __restrict__ context)
{
    int e = blockIdx.x * 256 + threadIdx.x;
    int s_begin = blockIdx.y * 64;
    float acc = 0.f;
    #pragma unroll 4
    for (int s = s_begin; s < s_begin + 64; ++s)
        acc = fmaf(w[s], enc[(size_t)s * E_ + e], acc);
    atomicAdd(&context[e], acc);
}

// ---------------- K6: ht_tilda = tanh(W_ah @ [context, ht] + b_ah) ----------------
__global__ __launch_bounds__(64) void k6_htilda(
    const float* __restrict__ W_ah, const float* __restrict__ b_ah,
    const float* __restrict__ context, const float* __restrict__ ht,
    float* __restrict__ out_htt, float* __restrict__ ws_htt)
{
    int h = blockIdx.x;
    int lane = threadIdx.x;
    const float* row = W_ah + (size_t)h * (E_ + H_);
    float acc = 0.f;
    #pragma unroll
    for (int it = 0; it < 8; ++it) {
        int idx = (lane + it * 64) * 4;
        float4 wv = *(const float4*)(row + idx);
        float4 xv = (idx < E_) ? *(const float4*)(context + idx)
                               : *(const float4*)(ht + idx - E_);
        acc = fmaf(wv.x, xv.x, acc); acc = fmaf(wv.y, xv.y, acc);
        acc = fmaf(wv.z, xv.z, acc); acc = fmaf(wv.w, xv.w, acc);
    }
    #pragma unroll
    for (int m = 32; m; m >>= 1) acc += __shfl_down(acc, m, 64);
    if (lane == 0) {
        float val = tanhf(acc + b_ah[h]);
        out_htt[h] = val;
        ws_htt[h]  = val;
    }
}

// ---------------- K7: logits = W_out @ ht_tilda + b_out ----------------
__global__ __launch_bounds__(256) void k7_logits(
    const float* __restrict__ W_out, const float* __restrict__ b_out,
    const float* __restrict__ ht_tilda, float* __restrict__ logits)
{
    int row = blockIdx.x * 4 + (threadIdx.x >> 6);
    int lane = threadIdx.x & 63;
    const float* wr = W_out + (size_t)row * H_;
    float acc = 0.f;
    #pragma unroll
    for (int it = 0; it < 4; ++it) {
        int idx = (lane + it * 64) * 4;
        float4 wv = *(const float4*)(wr + idx);
        float4 hv = *(const float4*)(ht_tilda + idx);
        acc = fmaf(wv.x, hv.x, acc); acc = fmaf(wv.y, hv.y, acc);
        acc = fmaf(wv.z, hv.z, acc); acc = fmaf(wv.w, hv.w, acc);
    }
    #pragma unroll
    for (int m = 32; m; m >>= 1) acc += __shfl_down(acc, m, 64);
    if (lane == 0) logits[row] = acc + b_out[row];
}

// ---------------- K8: lse = logsumexp(logits) ----------------
__global__ __launch_bounds__(1024) void k8_lse(
    const float* __restrict__ logits, float* __restrict__ lse)
{
    __shared__ float sm[16];
    int tid = threadIdx.x;
    float m = -1e30f;
    for (int i = tid; i < V_; i += 1024) m = fmaxf(m, logits[i]);
    #pragma unroll
    for (int s = 32; s; s >>= 1) m = fmaxf(m, __shfl_xor(m, s, 64));
    if ((tid & 63) == 0) sm[tid >> 6] = m;
    __syncthreads();
    float m_all = sm[0];
    #pragma unroll
    for (int i = 1; i < 16; ++i) m_all = fmaxf(m_all, sm[i]);
    float sum = 0.f;
    for (int i = tid; i < V_; i += 1024) sum += expf(logits[i] - m_all);
    #pragma unroll
    for (int s = 32; s; s >>= 1) sum += __shfl_xor(sum, s, 64);
    __syncthreads();
    if ((tid & 63) == 0) sm[tid >> 6] = sum;
    __syncthreads();
    if (tid == 0) {
        float s_all = 0.f;
        #pragma unroll
        for (int i = 0; i < 16; ++i) s_all += sm[i];
        lse[0] = m_all + logf(s_all);
    }
}

// ---------------- K9: out = logits - lse ----------------
__global__ __launch_bounds__(256) void k9_logsoftmax(
    float* __restrict__ out, const float* __restrict__ lse)
{
    int i = blockIdx.x * 256 + threadIdx.x;
    if (i < V_) out[i] -= lse[0];
}

extern "C" void kernel_launch(void* const* d_in, const int* in_sizes, int n_in,
                              void* d_out, int out_size, void* d_ws, size_t ws_size,
                              hipStream_t stream) {
    const float* enc          = (const float*)d_in[0];
    const int*   word         = (const int*)  d_in[1];
    const float* last_context = (const float*)d_in[2];
    const float* h0           = (const float*)d_in[3];
    const float* c0           = (const float*)d_in[4];
    const float* emb          = (const float*)d_in[5];
    const float* W_ih         = (const float*)d_in[6];
    const float* W_hh         = (const float*)d_in[7];
    const float* b_ih         = (const float*)d_in[8];
    const float* b_hh         = (const float*)d_in[9];
    const float* W_attn       = (const float*)d_in[10];
    const float* b_attn       = (const float*)d_in[11];
    const float* v            = (const float*)d_in[12];
    const float* W_ah         = (const float*)d_in[13];
    const float* b_ah         = (const float*)d_in[14];
    const float* W_out        = (const float*)d_in[15];
    const float* b_out        = (const float*)d_in[16];

    float* out        = (float*)d_out;
    float* out_logits = out;                 // 32000
    float* out_ht     = out + V_;            // 1024
    float* out_c      = out + V_ + H_;       // 1024
    float* out_htt    = out + V_ + 2 * H_;   // 1024
    float* out_w      = out + V_ + 3 * H_;   // 2048

    float* ws        = (float*)d_ws;
    float* ws_ht     = ws;          // 1024
    float* ws_q      = ws + 1024;   // 1024
    float* ws_scores = ws + 2048;   // 2048
    float* ws_w      = ws + 4096;   // 2048
    float* ws_ctx    = ws + 6144;   // 1024
    float* ws_htt    = ws + 7168;   // 1024
    float* ws_lse    = ws + 8192;   // 1

    hipMemsetAsync(ws_scores, 0, S_ * sizeof(float), stream);
    hipMemsetAsync(ws_ctx,    0, E_ * sizeof(float), stream);

    k1_gates<<<1024, 256, 0, stream>>>(W_ih, W_hh, b_ih, b_hh, last_context, emb,
                                       word, h0, c0, out_ht, out_c, ws_ht);
    k2_q<<<1024, 64, 0, stream>>>(W_attn, b_attn, ws_ht, ws_q);
    k3_mfma<<<dim3(S_ / 128, H_ / 128), 256, 0, stream>>>(enc, W_attn, ws_q, v, ws_scores);
    k4_softmax<<<1, 256, 0, stream>>>(ws_scores, out_w, ws_w);
    k5_context<<<dim3(4, 32), 256, 0, stream>>>(enc, ws_w, ws_ctx);
    k6_htilda<<<1024, 64, 0, stream>>>(W_ah, b_ah, ws_ctx, ws_ht, out_htt, ws_htt);
    k7_logits<<<8000, 256, 0, stream>>>(W_out, b_out, ws_htt, out_logits);
    k8_lse<<<1, 1024, 0, stream>>>(out_logits, ws_lse);
    k9_logsoftmax<<<(V_ + 255) / 256, 256, 0, stream>>>(out_logits, ws_lse);
}

// Round 3
// 91.904 us; speedup vs baseline: 1.5049x; 1.2037x over previous
//
#include <hip/hip_runtime.h>
#include <math.h>

#define V_ 32000
#define E_ 1024
#define H_ 1024
#define S_ 2048

typedef __attribute__((ext_vector_type(8))) short bf16x8;
typedef __attribute__((ext_vector_type(8))) unsigned short u16x8;
typedef __attribute__((ext_vector_type(4))) float f32x4;

typedef __attribute__((address_space(1))) const unsigned int gu32;
typedef __attribute__((address_space(3))) unsigned int lu32;

__device__ __forceinline__ float sigmoidf_(float x) { return 1.0f / (1.0f + expf(-x)); }

__device__ __forceinline__ unsigned short f2bf(float f) {
    unsigned int u = __builtin_bit_cast(unsigned int, f);
    unsigned int r = (u + 0x7fffu + ((u >> 16) & 1u)) >> 16;
    return (unsigned short)r;
}

__device__ __forceinline__ u16x8 pack8(float4 a, float4 b) {
    u16x8 p;
    p[0] = f2bf(a.x); p[1] = f2bf(a.y); p[2] = f2bf(a.z); p[3] = f2bf(a.w);
    p[4] = f2bf(b.x); p[5] = f2bf(b.y); p[6] = f2bf(b.z); p[7] = f2bf(b.w);
    return p;
}

__device__ __forceinline__ void gload16(const void* g, void* l) {
    __builtin_amdgcn_global_load_lds((gu32*)g, (lu32*)l, 16, 0, 0);
}

// ---------------- K1: LSTM gates + cell (wave-per-gate-row) ----------------
__global__ __launch_bounds__(256) void k1_gates(
    const float* __restrict__ W_ih, const float* __restrict__ W_hh,
    const float* __restrict__ b_ih, const float* __restrict__ b_hh,
    const float* __restrict__ last_context, const float* __restrict__ emb,
    const int* __restrict__ word, const float* __restrict__ h0,
    const float* __restrict__ c0,
    float* __restrict__ out_ht, float* __restrict__ out_c,
    float* __restrict__ ws_ht)
{
    __shared__ float sbuf[4];
    int j = blockIdx.x;
    int tid = threadIdx.x, wave = tid >> 6, lane = tid & 63;
    const float* embrow = emb + (size_t)word[0] * E_;
    int row = j + wave * H_;
    const float* wi = W_ih + (size_t)row * (E_ + H_);
    const float* wh = W_hh + (size_t)row * H_;
    float acc = 0.f;
    #pragma unroll
    for (int it = 0; it < 8; ++it) {
        int idx = (lane + it * 64) * 4;
        float4 wv = *(const float4*)(wi + idx);
        float4 xv = (idx < H_) ? *(const float4*)(last_context + idx)
                               : *(const float4*)(embrow + (idx - H_));
        acc = fmaf(wv.x, xv.x, acc); acc = fmaf(wv.y, xv.y, acc);
        acc = fmaf(wv.z, xv.z, acc); acc = fmaf(wv.w, xv.w, acc);
    }
    #pragma unroll
    for (int it = 0; it < 4; ++it) {
        int idx = (lane + it * 64) * 4;
        float4 wv = *(const float4*)(wh + idx);
        float4 hv = *(const float4*)(h0 + idx);
        acc = fmaf(wv.x, hv.x, acc); acc = fmaf(wv.y, hv.y, acc);
        acc = fmaf(wv.z, hv.z, acc); acc = fmaf(wv.w, hv.w, acc);
    }
    #pragma unroll
    for (int m = 32; m; m >>= 1) acc += __shfl_down(acc, m, 64);
    if (lane == 0) sbuf[wave] = acc;
    __syncthreads();
    if (tid == 0) {
        float gi = sbuf[0] + b_ih[j]          + b_hh[j];
        float gf = sbuf[1] + b_ih[j + H_]     + b_hh[j + H_];
        float gg = sbuf[2] + b_ih[j + 2*H_]   + b_hh[j + 2*H_];
        float go = sbuf[3] + b_ih[j + 3*H_]   + b_hh[j + 3*H_];
        float c  = sigmoidf_(gf) * c0[j] + sigmoidf_(gi) * tanhf(gg);
        float ht = sigmoidf_(go) * tanhf(c);
        out_c[j]  = c;
        out_ht[j] = ht;
        ws_ht[j]  = ht;
    }
}

// ---------------- K2: q = Wa_h @ ht + b_attn ----------------
__global__ __launch_bounds__(64) void k2_q(
    const float* __restrict__ W_attn, const float* __restrict__ b_attn,
    const float* __restrict__ ht, float* __restrict__ q)
{
    int h = blockIdx.x;
    int lane = threadIdx.x;
    const float* row = W_attn + (size_t)h * (E_ + H_);
    float acc = 0.f;
    #pragma unroll
    for (int it = 0; it < 4; ++it) {
        int idx = (lane + it * 64) * 4;
        float4 wv = *(const float4*)(row + idx);
        float4 hv = *(const float4*)(ht + idx);
        acc = fmaf(wv.x, hv.x, acc); acc = fmaf(wv.y, hv.y, acc);
        acc = fmaf(wv.z, hv.z, acc); acc = fmaf(wv.w, hv.w, acc);
    }
    #pragma unroll
    for (int m = 32; m; m >>= 1) acc += __shfl_down(acc, m, 64);
    if (lane == 0) q[h] = acc + b_attn[h];
}

// ---------------- K3a: convert enc + Wa_e to bf16 ----------------
// 393216 16B-chunks total: 262144 enc + 131072 Wa_e. Grid 1536 x 256.
__global__ __launch_bounds__(256) void k3a_conv(
    const float* __restrict__ enc, const float* __restrict__ W_attn,
    unsigned short* __restrict__ encb, unsigned short* __restrict__ wab)
{
    int idx = blockIdx.x * 256 + threadIdx.x;
    const int ENC_CH = (S_ * E_) / 8;
    const float* src;
    unsigned short* dst;
    if (idx < ENC_CH) {
        src = enc + (size_t)idx * 8;
        dst = encb + (size_t)idx * 8;
    } else {
        int w = idx - ENC_CH;
        int h = w >> 7, off = (w & 127) * 8;
        src = W_attn + (size_t)h * (E_ + H_) + H_ + off;
        dst = wab + (size_t)h * E_ + off;
    }
    float4 a = *(const float4*)src;
    float4 b = *(const float4*)(src + 4);
    *(u16x8*)dst = pack8(a, b);
}

// ---------------- K3b: scores partials = tanh(enc @ Wa_e^T + q) @ v ----------------
// BM=128, BN=64, BK=64. Grid (16,16), 256 thr = 4 waves (2x2; wave tile 64x32).
// LDS double-buffered, staged via global_load_lds (linear dest); XOR chunk
// swizzle l = c ^ (row&7) applied to global SOURCE addr and to the read side.
__global__ __launch_bounds__(256) void k3b_gemm(
    const unsigned short* __restrict__ encb, const unsigned short* __restrict__ wab,
    const float* __restrict__ q, const float* __restrict__ v,
    float* __restrict__ spart)
{
    __shared__ unsigned short As[2][128 * 64];  // 16 KB per buf
    __shared__ unsigned short Bs[2][64 * 64];   //  8 KB per buf
    int s0 = blockIdx.x * 128, h0 = blockIdx.y * 64;
    int tid = threadIdx.x;
    int wave = tid >> 6, lane = tid & 63;
    int wr = (wave >> 1) * 64, wc = (wave & 1) * 32;

    // staging source addresses (pre-swizzled chunk)
    int srow = tid >> 3;                                  // 0..31
    int lch  = ((tid & 7) ^ (srow & 7)) * 8;              // logical chunk offset (shorts)
    const unsigned short* aSrc[4];
    #pragma unroll
    for (int jj = 0; jj < 4; ++jj)
        aSrc[jj] = encb + (size_t)(s0 + jj * 32 + srow) * E_ + lch;
    const unsigned short* bSrc[2];
    #pragma unroll
    for (int jj = 0; jj < 2; ++jj)
        bSrc[jj] = wab + (size_t)(h0 + jj * 32 + srow) * E_ + lch;

    // fragment read offsets (shorts)
    int fc = lane & 15, g = lane >> 4;
    int aRow[4], bRow[2], pc[2];
    #pragma unroll
    for (int m = 0; m < 4; ++m) aRow[m] = (wr + m * 16 + fc) * 64;
    #pragma unroll
    for (int n = 0; n < 2; ++n) bRow[n] = (wc + n * 16 + fc) * 64;
    #pragma unroll
    for (int kk = 0; kk < 2; ++kk) pc[kk] = ((kk * 4 + g) ^ (fc & 7)) * 8;

    f32x4 acc[4][2];
    #pragma unroll
    for (int m = 0; m < 4; ++m)
        #pragma unroll
        for (int n = 0; n < 2; ++n)
            acc[m][n] = (f32x4){0.f, 0.f, 0.f, 0.f};

    // prologue: stage tile 0
    #pragma unroll
    for (int jj = 0; jj < 4; ++jj) gload16(aSrc[jj], &As[0][jj * 2048 + tid * 8]);
    #pragma unroll
    for (int jj = 0; jj < 2; ++jj) gload16(bSrc[jj], &Bs[0][jj * 2048 + tid * 8]);
    __syncthreads();

    int cur = 0;
    for (int t = 0; t < 16; ++t) {
        if (t < 15) {
            int k0 = (t + 1) * 64;
            #pragma unroll
            for (int jj = 0; jj < 4; ++jj)
                gload16(aSrc[jj] + k0, &As[cur ^ 1][jj * 2048 + tid * 8]);
            #pragma unroll
            for (int jj = 0; jj < 2; ++jj)
                gload16(bSrc[jj] + k0, &Bs[cur ^ 1][jj * 2048 + tid * 8]);
        }
        #pragma unroll
        for (int kk = 0; kk < 2; ++kk) {
            bf16x8 af[4], bf2[2];
            #pragma unroll
            for (int m = 0; m < 4; ++m) af[m] = *(const bf16x8*)&As[cur][aRow[m] + pc[kk]];
            #pragma unroll
            for (int n = 0; n < 2; ++n) bf2[n] = *(const bf16x8*)&Bs[cur][bRow[n] + pc[kk]];
            #pragma unroll
            for (int m = 0; m < 4; ++m)
                #pragma unroll
                for (int n = 0; n < 2; ++n)
                    acc[m][n] = __builtin_amdgcn_mfma_f32_16x16x32_bf16(
                        af[m], bf2[n], acc[m][n], 0, 0, 0);
        }
        __syncthreads();
        cur ^= 1;
    }

    // epilogue: partial score rows for this (h-block, wave-half)
    float qv[2], vv[2];
    #pragma unroll
    for (int n = 0; n < 2; ++n) {
        int col = h0 + wc + n * 16 + fc;
        qv[n] = q[col];
        vv[n] = v[col];
    }
    int part = blockIdx.y * 2 + (wave & 1);
    #pragma unroll
    for (int m = 0; m < 4; ++m) {
        #pragma unroll
        for (int j = 0; j < 4; ++j) {
            float p = 0.f;
            #pragma unroll
            for (int n = 0; n < 2; ++n)
                p += tanhf(acc[m][n][j] + qv[n]) * vv[n];
            #pragma unroll
            for (int mask = 8; mask; mask >>= 1) p += __shfl_xor(p, mask, 64);
            if (fc == 0)
                spart[(size_t)(s0 + wr + m * 16 + g * 4 + j) * 32 + part] = p;
        }
    }
}

// ---------------- K4: w = softmax(sum spart) ; also zero ctx ----------------
__global__ __launch_bounds__(256) void k4_softmax(
    const float* __restrict__ spart, float* __restrict__ w_out,
    float* __restrict__ w_ws, float* __restrict__ ctx)
{
    __shared__ float sm[4];
    int tid = threadIdx.x;
    #pragma unroll
    for (int i = 0; i < 4; ++i) ctx[tid + i * 256] = 0.f;
    float x[8];
    float m = -1e30f;
    #pragma unroll
    for (int i = 0; i < 8; ++i) {
        int e = tid + i * 256;
        float acc = 0.f;
        #pragma unroll
        for (int c = 0; c < 8; ++c) {
            float4 pv = *(const float4*)&spart[(size_t)e * 32 + c * 4];
            acc += pv.x + pv.y + pv.z + pv.w;
        }
        x[i] = acc;
        m = fmaxf(m, acc);
    }
    #pragma unroll
    for (int s = 32; s; s >>= 1) m = fmaxf(m, __shfl_xor(m, s, 64));
    if ((tid & 63) == 0) sm[tid >> 6] = m;
    __syncthreads();
    m = fmaxf(fmaxf(sm[0], sm[1]), fmaxf(sm[2], sm[3]));
    float sum = 0.f;
    #pragma unroll
    for (int i = 0; i < 8; ++i) { x[i] = expf(x[i] - m); sum += x[i]; }
    #pragma unroll
    for (int s = 32; s; s >>= 1) sum += __shfl_xor(sum, s, 64);
    __syncthreads();
    if ((tid & 63) == 0) sm[tid >> 6] = sum;
    __syncthreads();
    sum = sm[0] + sm[1] + sm[2] + sm[3];
    float inv = 1.0f / sum;
    #pragma unroll
    for (int i = 0; i < 8; ++i) {
        float wv = x[i] * inv;
        w_out[tid + i * 256] = wv;
        w_ws[tid + i * 256]  = wv;
    }
}

// ---------------- K5: context = w @ enc ----------------
__global__ __launch_bounds__(256) void k5_context(
    const float* __restrict__ enc, const float* __restrict__ w,
    float* __restrict__ context)
{
    int e = blockIdx.x * 256 + threadIdx.x;
    int s_begin = blockIdx.y * 64;
    float acc = 0.f;
    #pragma unroll 4
    for (int s = s_begin; s < s_begin + 64; ++s)
        acc = fmaf(w[s], enc[(size_t)s * E_ + e], acc);
    atomicAdd(&context[e], acc);
}

// ---------------- K6: ht_tilda = tanh(W_ah @ [context, ht] + b_ah) ----------------
__global__ __launch_bounds__(64) void k6_htilda(
    const float* __restrict__ W_ah, const float* __restrict__ b_ah,
    const float* __restrict__ context, const float* __restrict__ ht,
    float* __restrict__ out_htt, float* __restrict__ ws_htt)
{
    int h = blockIdx.x;
    int lane = threadIdx.x;
    const float* row = W_ah + (size_t)h * (E_ + H_);
    float acc = 0.f;
    #pragma unroll
    for (int it = 0; it < 8; ++it) {
        int idx = (lane + it * 64) * 4;
        float4 wv = *(const float4*)(row + idx);
        float4 xv = (idx < E_) ? *(const float4*)(context + idx)
                               : *(const float4*)(ht + idx - E_);
        acc = fmaf(wv.x, xv.x, acc); acc = fmaf(wv.y, xv.y, acc);
        acc = fmaf(wv.z, xv.z, acc); acc = fmaf(wv.w, xv.w, acc);
    }
    #pragma unroll
    for (int m = 32; m; m >>= 1) acc += __shfl_down(acc, m, 64);
    if (lane == 0) {
        float val = tanhf(acc + b_ah[h]);
        out_htt[h] = val;
        ws_htt[h]  = val;
    }
}

// ---------------- K7: logits = W_out @ ht_tilda + b_out ----------------
__global__ __launch_bounds__(256) void k7_logits(
    const float* __restrict__ W_out, const float* __restrict__ b_out,
    const float* __restrict__ ht_tilda, float* __restrict__ logits)
{
    int row = blockIdx.x * 4 + (threadIdx.x >> 6);
    int lane = threadIdx.x & 63;
    const float* wr = W_out + (size_t)row * H_;
    float acc = 0.f;
    #pragma unroll
    for (int it = 0; it < 4; ++it) {
        int idx = (lane + it * 64) * 4;
        float4 wv = *(const float4*)(wr + idx);
        float4 hv = *(const float4*)(ht_tilda + idx);
        acc = fmaf(wv.x, hv.x, acc); acc = fmaf(wv.y, hv.y, acc);
        acc = fmaf(wv.z, hv.z, acc); acc = fmaf(wv.w, hv.w, acc);
    }
    #pragma unroll
    for (int m = 32; m; m >>= 1) acc += __shfl_down(acc, m, 64);
    if (lane == 0) logits[row] = acc + b_out[row];
}

// ---------------- K8: per-block online (max, sum) partials ----------------
// 64 blocks x 256 threads, 500 elems each.
__global__ __launch_bounds__(256) void k8_partial(
    const float* __restrict__ logits, float* __restrict__ part)
{
    __shared__ float smx[4], ssx[4];
    int b = blockIdx.x, tid = threadIdx.x;
    int base = b * 500;
    float m = -1e30f, s = 0.f;
    for (int i = tid; i < 500; i += 256) {
        float x = logits[base + i];
        float M = fmaxf(m, x);
        s = s * expf(m - M) + expf(x - M);
        m = M;
    }
    #pragma unroll
    for (int mask = 32; mask; mask >>= 1) {
        float om = __shfl_xor(m, mask, 64);
        float os = __shfl_xor(s, mask, 64);
        float M = fmaxf(m, om);
        s = s * expf(m - M) + os * expf(om - M);
        m = M;
    }
    if ((tid & 63) == 0) { smx[tid >> 6] = m; ssx[tid >> 6] = s; }
    __syncthreads();
    if (tid == 0) {
        float M = fmaxf(fmaxf(smx[0], smx[1]), fmaxf(smx[2], smx[3]));
        float S = ssx[0] * expf(smx[0] - M) + ssx[1] * expf(smx[1] - M)
                + ssx[2] * expf(smx[2] - M) + ssx[3] * expf(smx[3] - M);
        part[2 * b]     = M;
        part[2 * b + 1] = S;
    }
}

// ---------------- K9: combine partials -> lse; out -= lse ----------------
// 125 blocks x 256 threads.
__global__ __launch_bounds__(256) void k9_finish(
    float* __restrict__ out, const float* __restrict__ part)
{
    __shared__ float slse;
    int tid = threadIdx.x;
    if (tid < 64) {
        float m = part[2 * tid], s = part[2 * tid + 1];
        #pragma unroll
        for (int mask = 32; mask; mask >>= 1) {
            float om = __shfl_xor(m, mask, 64);
            float os = __shfl_xor(s, mask, 64);
            float M = fmaxf(m, om);
            s = s * expf(m - M) + os * expf(om - M);
            m = M;
        }
        if (tid == 0) slse = m + logf(s);
    }
    __syncthreads();
    out[blockIdx.x * 256 + tid] -= slse;
}

extern "C" void kernel_launch(void* const* d_in, const int* in_sizes, int n_in,
                              void* d_out, int out_size, void* d_ws, size_t ws_size,
                              hipStream_t stream) {
    const float* enc          = (const float*)d_in[0];
    const int*   word         = (const int*)  d_in[1];
    const float* last_context = (const float*)d_in[2];
    const float* h0           = (const float*)d_in[3];
    const float* c0           = (const float*)d_in[4];
    const float* emb          = (const float*)d_in[5];
    const float* W_ih         = (const float*)d_in[6];
    const float* W_hh         = (const float*)d_in[7];
    const float* b_ih         = (const float*)d_in[8];
    const float* b_hh         = (const float*)d_in[9];
    const float* W_attn       = (const float*)d_in[10];
    const float* b_attn       = (const float*)d_in[11];
    const float* v            = (const float*)d_in[12];
    const float* W_ah         = (const float*)d_in[13];
    const float* b_ah         = (const float*)d_in[14];
    const float* W_out        = (const float*)d_in[15];
    const float* b_out        = (const float*)d_in[16];

    float* out        = (float*)d_out;
    float* out_logits = out;                 // 32000
    float* out_ht     = out + V_;            // 1024
    float* out_c      = out + V_ + H_;       // 1024
    float* out_htt    = out + V_ + 2 * H_;   // 1024
    float* out_w      = out + V_ + 3 * H_;   // 2048

    float* ws        = (float*)d_ws;
    float* ws_ht     = ws;           // 1024
    float* ws_q      = ws + 1024;    // 1024
    float* ws_w      = ws + 2048;    // 2048
    float* ws_ctx    = ws + 4096;    // 1024
    float* ws_htt    = ws + 5120;    // 1024
    float* ws_part   = ws + 6144;    // 128
    float* ws_spart  = ws + 8192;    // 2048*32 = 65536
    unsigned short* encb = (unsigned short*)(ws + 73728);  // 2048*1024
    unsigned short* wab  = encb + (size_t)S_ * E_;         // 1024*1024

    k1_gates<<<1024, 256, 0, stream>>>(W_ih, W_hh, b_ih, b_hh, last_context, emb,
                                       word, h0, c0, out_ht, out_c, ws_ht);
    k2_q<<<1024, 64, 0, stream>>>(W_attn, b_attn, ws_ht, ws_q);
    k3a_conv<<<1536, 256, 0, stream>>>(enc, W_attn, encb, wab);
    k3b_gemm<<<dim3(S_ / 128, H_ / 64), 256, 0, stream>>>(encb, wab, ws_q, v, ws_spart);
    k4_softmax<<<1, 256, 0, stream>>>(ws_spart, out_w, ws_w, ws_ctx);
    k5_context<<<dim3(4, 32), 256, 0, stream>>>(enc, ws_w, ws_ctx);
    k6_htilda<<<1024, 64, 0, stream>>>(W_ah, b_ah, ws_ctx, ws_ht, out_htt, ws_htt);
    k7_logits<<<8000, 256, 0, stream>>>(W_out, b_out, ws_htt, out_logits);
    k8_partial<<<64, 256, 0, stream>>>(out_logits, ws_part);
    k9_finish<<<125, 256, 0, stream>>>(out_logits, ws_part);
}